// Round 5
// baseline (5943.312 us; speedup 1.0000x reference)
//
#include <hip/hip_runtime.h>
#include <hip/hip_bf16.h>
#include <stdint.h>

// Problem dims
#define B_   16
#define T_   4096
#define F_   47
#define HID_ 64
#define CH_  256
#define TG_  1024   // T/4
#define G3_  768    // 3*CH

using bf16x8 = __attribute__((ext_vector_type(8))) short;  // 8 bf16 (4 VGPRs)
using f32x4  = __attribute__((ext_vector_type(4))) float;  // 4 fp32 acc
using f32x2  = __attribute__((ext_vector_type(2))) float;
using f16x8  = __attribute__((ext_vector_type(8))) _Float16;
using h2     = __attribute__((ext_vector_type(2))) _Float16;

__device__ __forceinline__ short f2bf(float f) {
    union { float f; uint32_t u; } v; v.f = f;
    uint32_t u = v.u;
    uint32_t r = (u + 0x7fffu + ((u >> 16) & 1u)) >> 16;   // RNE
    return (short)r;
}
__device__ __forceinline__ float bf2f(short s) {
    union { uint32_t u; float f; } v; v.u = ((uint32_t)(uint16_t)s) << 16;
    return v.f;
}
__device__ __forceinline__ float fast_tanh(float x) {
    float e = __expf(2.f * x);           // inf-safe
    return 1.f - 2.f / (e + 1.f);
}
__device__ __forceinline__ float fast_sigmoid(float x) {
    return 1.f / (1.f + __expf(-x));
}

#if __has_builtin(__builtin_amdgcn_fdot2)
#define FDOT2(a, b, c) __builtin_amdgcn_fdot2((a), (b), (c), false)
#else
__device__ __forceinline__ float fdot2_emul(h2 a, h2 b, float c) {
    return c + (float)a[0] * (float)b[0] + (float)a[1] * (float)b[1];
}
#define FDOT2(a, b, c) fdot2_emul((a), (b), (c))
#endif

#if __has_builtin(__builtin_amdgcn_global_load_lds)
#define HAS_GLL 1
__device__ __forceinline__ void gl_lds16(const void* g, void* l) {
    __builtin_amdgcn_global_load_lds(
        (const __attribute__((address_space(1))) uint32_t*)g,
        (__attribute__((address_space(3))) uint32_t*)l, 16, 0, 0);
}
#else
#define HAS_GLL 0
#endif

// ---------------------------------------------------------------------------
// K1: conv1 (pointwise 47->64) + tanh, fp32 VALU, writes c1 as bf16
__global__ __launch_bounds__(256) void k1_conv1(const float* __restrict__ feat,
        const float* __restrict__ W1, const float* __restrict__ b1,
        short* __restrict__ c1) {
    __shared__ float sW[47 * 64];
    __shared__ float sF[4 * 47];
    int tid = threadIdx.x;
    int b = blockIdx.x >> 10, t0 = (blockIdx.x & 1023) * 4;
    if (tid < 188) sF[tid] = feat[((size_t)b * T_ + t0) * 47 + tid];
    for (int i = tid; i < 47 * 64; i += 256) {
        int f = i >> 6, h = i & 63;
        sW[i] = W1[h * 47 + f];
    }
    __syncthreads();
    int fr = tid >> 6, h = tid & 63;
    float acc = b1[h];
    #pragma unroll
    for (int f = 0; f < 47; ++f)
        acc += sF[fr * 47 + f] * sW[f * 64 + h];
    c1[((size_t)b * T_ + t0 + fr) * 64 + h] = f2bf(fast_tanh(acc));
}

// ---------------------------------------------------------------------------
// Weight prep (bf16 B^T layouts for the prelude GEMMs)
__global__ __launch_bounds__(256) void k_prep(const float* __restrict__ W2,
        const float* __restrict__ Wt, const float* __restrict__ Wih_f,
        short* __restrict__ W2t, short* __restrict__ Wtt, short* __restrict__ Wih) {
    int idx = blockIdx.x * 256 + threadIdx.x;
    if (idx < 256 * 512) {
        int o = idx >> 9, i = idx & 511, d = i >> 8, jj = i & 255;
        W2t[idx] = f2bf(W2[(size_t)o * 512 + jj * 2 + d]);
    }
    {
        int n = idx >> 8, ic = idx & 255, o = n & 255, kp = n >> 8;
        Wtt[idx] = f2bf(Wt[(size_t)ic * 1024 + o * 4 + kp]);
    }
    if (idx < G3_ * CH_)
        Wih[idx] = f2bf(Wih_f[idx]);
}

// ---------------------------------------------------------------------------
// K2: conv2 (k=2 causal) as GEMM M=16384,K=512,N=256 + tanh.
__global__ __launch_bounds__(256) void k2_conv2(const short* __restrict__ c1,
        const short* __restrict__ W2t, const float* __restrict__ b2,
        short* __restrict__ y2) {
    int tid = threadIdx.x, w = tid >> 6, l = tid & 63;
    int lane16 = l & 15, quad = l >> 4;
    int mt = blockIdx.x * 4 + w;
    int row = mt * 16 + lane16;
    int tg = row & 1023;
    const short* Arow = c1 + (size_t)row * 256 - 256;
    bf16x8 zero8 = {0,0,0,0,0,0,0,0};
    bf16x8 af[16];
    #pragma unroll
    for (int kt = 0; kt < 16; ++kt) {
        int i0 = kt * 32 + quad * 8;
        bool masked = (tg == 0) && (kt < 8);
        const short* p = masked ? c1 : (Arow + i0);
        bf16x8 v = *(const bf16x8*)p;
        af[kt] = masked ? zero8 : v;
    }
    #pragma unroll
    for (int nt = 0; nt < 16; ++nt) {
        int n = nt * 16 + lane16;
        f32x4 acc = {0.f, 0.f, 0.f, 0.f};
        const short* Brow = W2t + (size_t)n * 512 + quad * 8;
        #pragma unroll
        for (int kt = 0; kt < 16; ++kt) {
            bf16x8 bf = *(const bf16x8*)(Brow + kt * 32);
            acc = __builtin_amdgcn_mfma_f32_16x16x32_bf16(af[kt], bf, acc, 0, 0, 0);
        }
        float bias = b2[n];
        #pragma unroll
        for (int r = 0; r < 4; ++r) {
            int mrow = mt * 16 + quad * 4 + r;
            y2[(size_t)mrow * 256 + n] = f2bf(fast_tanh(acc[r] + bias));
        }
    }
}

// ---------------------------------------------------------------------------
// K3a: tconv as GEMM M=16384,K=256,N=1024 + tanh -> c3 bf16.
__global__ __launch_bounds__(256) void k3a_tconv(const short* __restrict__ y2,
        const short* __restrict__ Wtt, const float* __restrict__ bt,
        short* __restrict__ c3) {
    int tid = threadIdx.x, w = tid >> 6, l = tid & 63;
    int lane16 = l & 15, quad = l >> 4;
    int mt = blockIdx.x;
    int row = mt * 16 + lane16;
    const short* Arow = y2 + (size_t)row * 256 + quad * 8;
    bf16x8 af[8];
    #pragma unroll
    for (int kt = 0; kt < 8; ++kt) af[kt] = *(const bf16x8*)(Arow + kt * 32);
    #pragma unroll
    for (int nt2 = 0; nt2 < 16; ++nt2) {
        int n = (w * 16 + nt2) * 16 + lane16;
        f32x4 acc = {0.f, 0.f, 0.f, 0.f};
        const short* Brow = Wtt + (size_t)n * 256 + quad * 8;
        #pragma unroll
        for (int kt = 0; kt < 8; ++kt) {
            bf16x8 bf = *(const bf16x8*)(Brow + kt * 32);
            acc = __builtin_amdgcn_mfma_f32_16x16x32_bf16(af[kt], bf, acc, 0, 0, 0);
        }
        int kp = n >> 8, o = n & 255;
        float bias = bt[o];
        #pragma unroll
        for (int r = 0; r < 4; ++r) {
            int mrow = mt * 16 + quad * 4 + r;
            int bb = mrow >> 10, tgg = mrow & 1023;
            c3[(((size_t)bb * TG_ + tgg) * 4 + kp) * 256 + o] =
                f2bf(fast_tanh(acc[r] + bias));
        }
    }
}

// ---------------------------------------------------------------------------
// K3b: x-projection GEMM M=65536,K=256,N=768 (+b_ih) -> gates bf16.
__global__ __launch_bounds__(256) void k3b_xproj(const short* __restrict__ c3,
        const short* __restrict__ Wih, const float* __restrict__ b_ih,
        short* __restrict__ gates) {
    int tid = threadIdx.x, w = tid >> 6, l = tid & 63;
    int lane16 = l & 15, quad = l >> 4;
    int mt = blockIdx.x;
    int row = mt * 16 + lane16;
    const short* Arow = c3 + (size_t)row * 256 + quad * 8;
    bf16x8 af[8];
    #pragma unroll
    for (int kt = 0; kt < 8; ++kt) af[kt] = *(const bf16x8*)(Arow + kt * 32);
    #pragma unroll
    for (int nt2 = 0; nt2 < 12; ++nt2) {
        int n = (w * 12 + nt2) * 16 + lane16;
        f32x4 acc = {0.f, 0.f, 0.f, 0.f};
        const short* Brow = Wih + (size_t)n * 256 + quad * 8;
        #pragma unroll
        for (int kt = 0; kt < 8; ++kt) {
            bf16x8 bf = *(const bf16x8*)(Brow + kt * 32);
            acc = __builtin_amdgcn_mfma_f32_16x16x32_bf16(af[kt], bf, acc, 0, 0, 0);
        }
        float bias = b_ih[n];
        #pragma unroll
        for (int r = 0; r < 4; ++r) {
            int mrow = mt * 16 + quad * 4 + r;
            gates[(size_t)mrow * G3_ + n] = f2bf(acc[r] + bias);
        }
    }
}

// ---------------------------------------------------------------------------
// K4: persistent GRU via v_dot2_f32_f16 — 1 block/batch, 1024 thr (16 waves,
// 4 waves/SIMD at the 128-VGPR cap). W_hh f16 in registers, 96 h2/thread:
// q=tid&7 owns h-range [q*32,q*32+32), n0=tid>>3 owns outputs {n0+128k,k<6}.
// Per-SIMD issue floor: 4 waves x 96 fdot2 x 2cyc = 768 cyc/step.
// Partials via bank-padded LDS; gates stream 16 steps/GLL batch.
__global__ __launch_bounds__(1024, 4) void k4_gru_dot2(const float* __restrict__ W_hh,
        const float* __restrict__ b_hh, const short* __restrict__ gates,
        float* __restrict__ out) {
    __shared__ __align__(16) short gxb[2][16][G3_];  // 48KB gate ring (bf16)
    __shared__ __align__(16) float part[8 * 776];    // 24.8KB padded partials
    __shared__ __align__(16) float ob[8 * 256];      // 8KB out staging
    __shared__ __align__(16) short hq_s[8 * 40];     // h f16, 64B seg + 16B pad

    int tid = threadIdx.x;
    int q = tid & 7, n0 = tid >> 3;                  // q: K-eighth, n0: 0..127
    int b = blockIdx.x;

    // ---- W_hh -> f16-pair registers (one-time): rows n0+128k, cols q*32..+31
    h2 wreg[6][16];
    #pragma unroll
    for (int k = 0; k < 6; ++k) {
        const float2* row = (const float2*)(W_hh + ((size_t)(n0 + k * 128)) * 256 + q * 32);
        #pragma unroll
        for (int j = 0; j < 16; ++j) {
            float2 v = row[j];
            h2 p; p[0] = (_Float16)v.x; p[1] = (_Float16)v.y;
            wreg[k][j] = p;
        }
    }

    float h_reg = 0.f, bhr = 0.f, bhz = 0.f, bhn = 0.f;
    if (tid < 256) {
        bhr = b_hh[tid]; bhz = b_hh[256 + tid]; bhn = b_hh[512 + tid];
    }
    if (tid < 320) hq_s[tid] = 0;                    // h = 0 (f16, covers pads)

    const char* gbytes = (const char*)(gates + (size_t)b * T_ * G3_);

    // prologue: steps 0..15 -> ring half 0 (24KB)
#if HAS_GLL
    {
        char* dst = (char*)&gxb[0][0][0];
        gl_lds16(gbytes + tid * 16, dst + (tid >> 6) * 1024);
        if (tid < 512)
            gl_lds16(gbytes + 16384 + tid * 16, dst + 16384 + (tid >> 6) * 1024);
    }
#else
    {
        const uint32_t* g32 = (const uint32_t*)gbytes;
        uint32_t* d = (uint32_t*)&gxb[0][0][0];
        #pragma unroll
        for (int i = 0; i < 6; ++i) d[tid + i * 1024] = g32[tid + i * 1024];
    }
#endif
    __syncthreads();

    float* outb = out + (size_t)b * T_ * CH_;
    for (int s = 0; s < T_; ++s) {
        bool grp0 = ((s & 15) == 0) && (s + 16 < T_);
#if HAS_GLL
        if (grp0) {   // async stage next 16 steps into the other ring half
            const char* src = gbytes + (size_t)(s + 16) * 1536;
            char* dst = (char*)&gxb[((s >> 4) + 1) & 1][0][0];
            gl_lds16(src + tid * 16, dst + (tid >> 6) * 1024);
            if (tid < 512)
                gl_lds16(src + 16384 + tid * 16, dst + 16384 + (tid >> 6) * 1024);
        }
#else
        uint32_t pf[6];
        if (grp0) {
            const uint32_t* src = (const uint32_t*)(gbytes + (size_t)(s + 16) * 1536);
            #pragma unroll
            for (int i = 0; i < 6; ++i) pf[i] = src[tid + i * 1024];
        }
#endif

        // ---- dot2 phase: 96 fdot2/thread; h-quarter via padded ds_read_b128
        float acc[6] = {0.f, 0.f, 0.f, 0.f, 0.f, 0.f};
        #pragma unroll
        for (int c = 0; c < 4; ++c) {
            f16x8 v = *(const f16x8*)&hq_s[q * 40 + c * 8];
            #pragma unroll
            for (int p2 = 0; p2 < 4; ++p2) {
                h2 hp; hp[0] = v[p2 * 2]; hp[1] = v[p2 * 2 + 1];
                #pragma unroll
                for (int k = 0; k < 6; ++k)
                    acc[k] = FDOT2(wreg[k][c * 4 + p2], hp, acc[k]);
            }
        }
        #pragma unroll
        for (int k = 0; k < 6; ++k)
            part[q * 776 + n0 + k * 128] = acc[k];
        __syncthreads();   // b1

#if !HAS_GLL
        if (grp0) {
            uint32_t* d = (uint32_t*)&gxb[((s >> 4) + 1) & 1][0][0];
            #pragma unroll
            for (int i = 0; i < 6; ++i) d[tid + i * 1024] = pf[i];
        }
#endif
        // ---- elementwise on threads < 256
        if (tid < 256) {
            const short* gx = &gxb[(s >> 4) & 1][s & 15][0];
            float gr = 0.f, gz = 0.f, gn = 0.f;
            #pragma unroll
            for (int qq = 0; qq < 8; ++qq) {
                gr += part[qq * 776 + tid];
                gz += part[qq * 776 + 256 + tid];
                gn += part[qq * 776 + 512 + tid];
            }
            float xr = bf2f(gx[tid]), xz = bf2f(gx[256 + tid]), xn = bf2f(gx[512 + tid]);
            float r = fast_sigmoid(xr + gr + bhr);
            float z = fast_sigmoid(xz + gz + bhz);
            float nn = fast_tanh(xn + r * (gn + bhn));
            h_reg = (1.f - z) * nn + z * h_reg;
            union { _Float16 f; short u; } cv; cv.f = (_Float16)h_reg;
            hq_s[(tid >> 5) * 40 + (tid & 31)] = cv.u;
            ob[(s & 7) * 256 + tid] = h_reg;
        }
        __syncthreads();   // b2

        // ---- out flush once per 8 steps, coalesced f32x2
        if ((s & 7) == 7) {
            f32x2 v = *(const f32x2*)&ob[tid * 2];
            *(f32x2*)&outb[(size_t)(s - 7 + (tid >> 7)) * 256 + (tid & 127) * 2] = v;
        }
    }
}

// ---------------------------------------------------------------------------
extern "C" void kernel_launch(void* const* d_in, const int* in_sizes, int n_in,
                              void* d_out, int out_size, void* d_ws, size_t ws_size,
                              hipStream_t stream) {
    const float* feat  = (const float*)d_in[0];
    const float* W1    = (const float*)d_in[1];
    const float* b1    = (const float*)d_in[2];
    const float* W2    = (const float*)d_in[3];
    const float* b2    = (const float*)d_in[4];
    const float* Wt    = (const float*)d_in[5];
    const float* bt    = (const float*)d_in[6];
    const float* Wih_f = (const float*)d_in[7];
    const float* Whh   = (const float*)d_in[8];
    const float* bih   = (const float*)d_in[9];
    const float* bhh   = (const float*)d_in[10];
    float* out = (float*)d_out;

    // ws layout (135.4 MB):
    //   [0, 33.5M)      c3 bf16 (c1 aliases first 8.4M; c1 dead after K2)
    //   [33.5M, 134.2M) gates bf16 (y2 aliases first 8.4M; y2 dead after K3a)
    //   [134.2M, ...)   W2t / Wtt / Wih bf16
    char* ws = (char*)d_ws;
    short* c3    = (short*)(ws);
    short* c1    = (short*)(ws);
    short* gates = (short*)(ws + 33554432);
    short* y2    = (short*)(ws + 33554432);
    short* W2t   = (short*)(ws + 134217728);
    short* Wtt   = (short*)(ws + 134217728 + 262144);
    short* Wih   = (short*)(ws + 134217728 + 262144 + 524288);

    k1_conv1   <<<16384, 256, 0, stream>>>(feat, W1, b1, c1);
    k_prep     <<<1024, 256, 0, stream>>>(W2, Wt, Wih_f, W2t, Wtt, Wih);
    k2_conv2   <<<256,  256, 0, stream>>>(c1, W2t, b2, y2);
    k3a_tconv  <<<1024, 256, 0, stream>>>(y2, Wtt, bt, c3);      // kills c1
    k3b_xproj  <<<4096, 256, 0, stream>>>(c3, Wih, bih, gates);  // kills y2
    k4_gru_dot2<<<16,  1024, 0, stream>>>(Whh, bhh, gates, out);
}